// Round 7
// baseline (560.333 us; speedup 1.0000x reference)
//
#include <hip/hip_runtime.h>
#include <math.h>

#define BB 32
#define LL 512
#define HH 768
#define NN 64
#define NLAYERS 4

typedef unsigned short ushort;
typedef __attribute__((ext_vector_type(8))) short bf16x8;
typedef __attribute__((ext_vector_type(4))) float f32x4;
typedef __attribute__((ext_vector_type(4))) ushort u16x4;

static __device__ __forceinline__ ushort f2bf(float f) {
  union { float f; unsigned u; } v; v.f = f;
  unsigned r = (v.u + 0x7FFF + ((v.u >> 16) & 1)) >> 16;   // RNE
  return (ushort)r;
}
static __device__ __forceinline__ float bf2f(ushort u) {
  union { unsigned u; float f; } v; v.u = ((unsigned)u) << 16; return v.f;
}
static __device__ __forceinline__ void gload16(const void* g, void* l) {
  __builtin_amdgcn_global_load_lds(
      (const __attribute__((address_space(1))) unsigned int*)g,
      (__attribute__((address_space(3))) unsigned int*)l, 16, 0, 0);
}
static __device__ __forceinline__ float hw_sin(float f) {
  float r; asm("v_sin_f32 %0, %1" : "=v"(r) : "v"(f)); return r;
}
static __device__ __forceinline__ float hw_cos(float f) {
  float r; asm("v_cos_f32 %0, %1" : "=v"(r) : "v"(f)); return r;
}

// ---------------------------------------------------------------------------
// compute_k v4: one wg per (il,h).  Phase 0: all 4 waves (lane=n) build
// vpow[t][n] = q^{8t} (wave w fills t=16w..16w+15 from start q^{128w}) into
// XOR-swizzled LDS (col n^t -> conflict-free both phases).  Phase 1: wave w
// sums n in [16w,16w+16), lane=t, 8-step q-recurrence; cross-wave reduce via
// padded LDS.  rev[i] = bf16(Kb[1023-i]); Kb[512+d]=K0[d], Kb[511-m]=K1[m].
// ---------------------------------------------------------------------------
__global__ __launch_bounds__(256) void compute_k_kernel(
    const float* __restrict__ log_dt, const float* __restrict__ A_re,
    const float* __restrict__ A_im, const float* __restrict__ C_re,
    const float* __restrict__ C_im, ushort* __restrict__ rev) {
  __shared__ float vr_[64 * 64];    // 16 KB
  __shared__ float vi_[64 * 64];    // 16 KB
  __shared__ float ctab[64][8];     // 2 KB
  __shared__ float red[3][64][17];  // 12.75 KB
  int tid = threadIdx.x;
  int wid = tid >> 6, lane = tid & 63;
  int blk = blockIdx.x;             // il*HH + h
  int il = blk / HH, h = blk - il * HH;
  {
    int n = lane;
    float dt = expf(log_dt[blk]);
    float a_re = -expf(A_re[(size_t)blk * NN + n]);
    float a_im = A_im[(size_t)blk * NN + n];
    float er = dt * a_re, ei = dt * a_im;
    float ea = __builtin_amdgcn_exp2f(er * 1.4426950408889634f);
    float fr = ei * 0.15915494309189535f;    // revolutions
    fr = fr - floorf(fr);
    float sv = hw_sin(fr), cv = hw_cos(fr);
    float qr = ea * cv, qi = ea * sv;
    if (wid == 0) {
      float e1r = qr - 1.f, e1i = qi;
      float den = a_re * a_re + a_im * a_im;
      float wr = (e1r * a_re + e1i * a_im) / den;
      float wi = (e1i * a_re - e1r * a_im) / den;
      size_t c0 = ((size_t)(il * 2 + 0) * HH + h) * NN + n;
      size_t c1 = ((size_t)(il * 2 + 1) * HH + h) * NN + n;
      float c0r = C_re[c0], c0i = C_im[c0];
      float c1r = C_re[c1], c1i = C_im[c1];
      ctab[n][0] = qr; ctab[n][1] = qi;
      ctab[n][2] = 2.f * (c0r * wr - c0i * wi);
      ctab[n][3] = 2.f * (c0r * wi + c0i * wr);
      ctab[n][4] = 2.f * (c1r * wr - c1i * wi);
      ctab[n][5] = 2.f * (c1r * wi + c1i * wr);
    }
    float pr = qr, pi = qi;
    float q8r = 0.f, q8i = 0.f, q128r = 0.f, q128i = 0.f, q256r = 0.f, q256i = 0.f;
#pragma unroll
    for (int j = 0; j < 8; ++j) {
      float nr = pr * pr - pi * pi, ni = 2.f * pr * pi;
      pr = nr; pi = ni;                       // q^(2^(j+1))
      if (j == 2) { q8r = pr; q8i = pi; }
      if (j == 6) { q128r = pr; q128i = pi; }
      if (j == 7) { q256r = pr; q256i = pi; }
    }
    float sr, si;
    if (wid == 0)      { sr = 1.f;   si = 0.f; }
    else if (wid == 1) { sr = q128r; si = q128i; }
    else if (wid == 2) { sr = q256r; si = q256i; }
    else { sr = q128r * q256r - q128i * q256i; si = q128r * q256i + q128i * q256r; }
#pragma unroll
    for (int j = 0; j < 16; ++j) {
      int t = wid * 16 + j;
      vr_[t * 64 + (n ^ t)] = sr;
      vi_[t * 64 + (n ^ t)] = si;
      float nr = sr * q8r - si * q8i, ni = sr * q8i + si * q8r;
      sr = nr; si = ni;
    }
  }
  __syncthreads();
  float k0[8], k1[8];
#pragma unroll
  for (int s = 0; s < 8; ++s) { k0[s] = 0.f; k1[s] = 0.f; }
  int t = lane;
  for (int nn = 0; nn < 16; ++nn) {
    int n = wid * 16 + nn;
    float4 cA = *(const float4*)&ctab[n][0];       // qr,qi,c0wr,c0wi (broadcast)
    float c1wr = ctab[n][4], c1wi = ctab[n][5];
    float vr = vr_[t * 64 + (n ^ t)];
    float vi = vi_[t * 64 + (n ^ t)];
#pragma unroll
    for (int s = 0; s < 8; ++s) {
      k0[s] = fmaf(cA.z, vr, fmaf(-cA.w, vi, k0[s]));
      k1[s] = fmaf(c1wr, vr, fmaf(-c1wi, vi, k1[s]));
      float nr = vr * cA.x - vi * cA.y, ni = vr * cA.y + vi * cA.x;
      vr = nr; vi = ni;
    }
  }
  if (wid > 0) {
#pragma unroll
    for (int s = 0; s < 8; ++s) {
      red[wid - 1][lane][s] = k0[s];
      red[wid - 1][lane][8 + s] = k1[s];
    }
  }
  __syncthreads();
  if (wid == 0) {
#pragma unroll
    for (int w = 0; w < 3; ++w)
#pragma unroll
      for (int s = 0; s < 8; ++s) {
        k0[s] += red[w][lane][s];
        k1[s] += red[w][lane][8 + s];
      }
    ushort* row = rev + ((size_t)blk << 10);
    bf16x8 o0, o1;
#pragma unroll
    for (int i = 0; i < 8; ++i) {
      o0[i] = (short)f2bf(k0[7 - i]);   // rev[504-8t+i] = K0[8t+7-i]
      o1[i] = (short)f2bf(k1[i]);       // rev[512+8t+i] = K1[8t+i]
    }
    *(bf16x8*)(row + 504 - 8 * t) = o0;
    *(bf16x8*)(row + 512 + 8 * t) = o1;
  }
}

// ---------------------------------------------------------------------------
// Wout fp32 -> bf16 (once)
// ---------------------------------------------------------------------------
__global__ __launch_bounds__(256) void wcast_kernel(
    const float* __restrict__ W, ushort* __restrict__ Wbf) {
  size_t i = ((size_t)blockIdx.x * 256 + threadIdx.x) * 8;
  float4 a = *(const float4*)&W[i];
  float4 c = *(const float4*)&W[i + 4];
  ushort o[8] = {f2bf(a.x), f2bf(a.y), f2bf(a.z), f2bf(a.w),
                 f2bf(c.x), f2bf(c.y), f2bf(c.z), f2bf(c.w)};
  *(bf16x8*)&Wbf[i] = *(bf16x8*)o;
}

// ---------------------------------------------------------------------------
// Fused LN1 * mask + transpose + bf16: X f32 [B,L,H] -> U bf16 [B,H,L]
// (layer 0 only)
// ---------------------------------------------------------------------------
__global__ __launch_bounds__(256) void ln_t_kernel(
    const float* __restrict__ X, const float* __restrict__ w,
    const float* __restrict__ b, const int* __restrict__ mask,
    ushort* __restrict__ U) {
  __shared__ ushort tile[32][772];
  int bb = blockIdx.y;
  int l0 = blockIdx.x << 5;
  int wv = threadIdx.x >> 6, lane = threadIdx.x & 63;
  const float4* w4 = (const float4*)w;
  const float4* b4 = (const float4*)b;
  float4 WW[3], BV[3];
#pragma unroll
  for (int m = 0; m < 3; ++m) { WW[m] = w4[lane + 64 * m]; BV[m] = b4[lane + 64 * m]; }
#pragma unroll
  for (int i = 0; i < 8; ++i) {
    int r = (wv << 3) + i;
    size_t rowi = (size_t)bb * LL + l0 + r;
    const float4* xr = (const float4*)(X + rowi * HH);
    float4 v[3];
    float s = 0.f, s2 = 0.f;
#pragma unroll
    for (int m = 0; m < 3; ++m) {
      v[m] = xr[lane + 64 * m];
      s  += v[m].x + v[m].y + v[m].z + v[m].w;
      s2 += v[m].x * v[m].x + v[m].y * v[m].y + v[m].z * v[m].z + v[m].w * v[m].w;
    }
#pragma unroll
    for (int off = 32; off >= 1; off >>= 1) {
      s  += __shfl_xor(s, off);
      s2 += __shfl_xor(s2, off);
    }
    float mu  = s * (1.f / HH);
    float var = s2 * (1.f / HH) - mu * mu;
    float rs  = rsqrtf(var + 1e-5f);
    float mf  = (float)mask[rowi];
#pragma unroll
    for (int m = 0; m < 3; ++m) {
      u16x4 o;
      o.x = f2bf(((v[m].x - mu) * rs * WW[m].x + BV[m].x) * mf);
      o.y = f2bf(((v[m].y - mu) * rs * WW[m].y + BV[m].y) * mf);
      o.z = f2bf(((v[m].z - mu) * rs * WW[m].z + BV[m].z) * mf);
      o.w = f2bf(((v[m].w - mu) * rs * WW[m].w + BV[m].w) * mf);
      *(u16x4*)&tile[r][(lane + 64 * m) << 2] = o;
    }
  }
  __syncthreads();
#pragma unroll
  for (int it = 0; it < 3; ++it) {
    int h = it * 256 + threadIdx.x;
    ushort* dst = U + (((size_t)bb * HH + h) << 9) + l0;
#pragma unroll
    for (int c = 0; c < 4; ++c) {
      bf16x8 o;
#pragma unroll
      for (int j = 0; j < 8; ++j) o[j] = (short)tile[c * 8 + j][h];
      *(bf16x8*)(dst + (c << 3)) = o;
    }
  }
}

// ---------------------------------------------------------------------------
// Boundary fuse: out_bf = base + LN2(Gbf);  U = transpose(bf16(LN1(out)*mask))
// BASE_F32: base is f32 (layer 0) else bf16 residual stream.
// ---------------------------------------------------------------------------
template <bool BASE_F32>
__global__ __launch_bounds__(256) void res_lnt_kernel(
    const ushort* __restrict__ Gbf, const float* __restrict__ w2,
    const float* __restrict__ b2, const void* __restrict__ base_,
    ushort* __restrict__ outbf, const int* __restrict__ mask,
    const float* __restrict__ w1, const float* __restrict__ b1,
    ushort* __restrict__ U) {
  __shared__ ushort tile[32][772];
  int bb = blockIdx.y;
  int l0 = blockIdx.x << 5;
  int wv = threadIdx.x >> 6, lane = threadIdx.x & 63;
  const float4* w14 = (const float4*)w1;
  const float4* b14 = (const float4*)b1;
  const float4* w24 = (const float4*)w2;
  const float4* b24 = (const float4*)b2;
  float4 W1[3], B1[3], W2[3], B2[3];
#pragma unroll
  for (int m = 0; m < 3; ++m) {
    W1[m] = w14[lane + 64 * m]; B1[m] = b14[lane + 64 * m];
    W2[m] = w24[lane + 64 * m]; B2[m] = b24[lane + 64 * m];
  }
#pragma unroll
  for (int i = 0; i < 8; ++i) {
    int r = (wv << 3) + i;
    size_t rowi = (size_t)bb * LL + l0 + r;
    const u16x4* gr = (const u16x4*)(Gbf + rowi * HH);
    float gv[12];
    float s = 0.f, s2 = 0.f;
#pragma unroll
    for (int m = 0; m < 3; ++m) {
      u16x4 q = gr[lane + 64 * m];
#pragma unroll
      for (int j = 0; j < 4; ++j) {
        float f = bf2f(q[j]);
        gv[m * 4 + j] = f;
        s += f; s2 += f * f;
      }
    }
#pragma unroll
    for (int off = 32; off >= 1; off >>= 1) {
      s  += __shfl_xor(s, off);
      s2 += __shfl_xor(s2, off);
    }
    float mu2  = s * (1.f / HH);
    float var2 = s2 * (1.f / HH) - mu2 * mu2;
    float rs2  = rsqrtf(var2 + 1e-5f);
    float ov[12];
    float t1 = 0.f, t2 = 0.f;
#pragma unroll
    for (int m = 0; m < 3; ++m) {
      float bvv[4];
      if (BASE_F32) {
        float4 bv = ((const float4*)((const float*)base_ + rowi * HH))[lane + 64 * m];
        bvv[0] = bv.x; bvv[1] = bv.y; bvv[2] = bv.z; bvv[3] = bv.w;
      } else {
        u16x4 bq = ((const u16x4*)((const ushort*)base_ + rowi * HH))[lane + 64 * m];
#pragma unroll
        for (int j = 0; j < 4; ++j) bvv[j] = bf2f(bq[j]);
      }
      u16x4 ob;
#pragma unroll
      for (int j = 0; j < 4; ++j) {
        float o = bvv[j] + (gv[m * 4 + j] - mu2) * rs2 * ((const float*)&W2[m])[j]
                  + ((const float*)&B2[m])[j];
        ov[m * 4 + j] = o;
        ob[j] = f2bf(o);
        t1 += o; t2 += o * o;
      }
      ((u16x4*)(outbf + rowi * HH))[lane + 64 * m] = ob;
    }
#pragma unroll
    for (int off = 32; off >= 1; off >>= 1) {
      t1 += __shfl_xor(t1, off);
      t2 += __shfl_xor(t2, off);
    }
    float mu1  = t1 * (1.f / HH);
    float var1 = t2 * (1.f / HH) - mu1 * mu1;
    float rs1  = rsqrtf(var1 + 1e-5f);
    float mf   = (float)mask[rowi];
#pragma unroll
    for (int m = 0; m < 3; ++m) {
      u16x4 o;
      o.x = f2bf(((ov[m * 4 + 0] - mu1) * rs1 * W1[m].x + B1[m].x) * mf);
      o.y = f2bf(((ov[m * 4 + 1] - mu1) * rs1 * W1[m].y + B1[m].y) * mf);
      o.z = f2bf(((ov[m * 4 + 2] - mu1) * rs1 * W1[m].z + B1[m].z) * mf);
      o.w = f2bf(((ov[m * 4 + 3] - mu1) * rs1 * W1[m].w + B1[m].w) * mf);
      *(u16x4*)&tile[r][(lane + 64 * m) << 2] = o;
    }
  }
  __syncthreads();
#pragma unroll
  for (int it = 0; it < 3; ++it) {
    int h = it * 256 + threadIdx.x;
    ushort* dst = U + (((size_t)bb * HH + h) << 9) + l0;
#pragma unroll
    for (int c = 0; c < 4; ++c) {
      bf16x8 o;
#pragma unroll
      for (int j = 0; j < 8; ++j) o[j] = (short)tile[c * 8 + j][h];
      *(bf16x8*)(dst + (c << 3)) = o;
    }
  }
}

// ---------------------------------------------------------------------------
// Final: out_f32 = base_bf + LN2(Gbf)
// ---------------------------------------------------------------------------
__global__ __launch_bounds__(256) void ln_res_kernel(
    const ushort* __restrict__ Gbf, const float* __restrict__ w,
    const float* __restrict__ b, const ushort* __restrict__ basebf,
    float* __restrict__ out) {
  int wv = threadIdx.x >> 6, lane = threadIdx.x & 63;
  size_t r = (size_t)blockIdx.x * 4 + wv;
  const u16x4* gr = (const u16x4*)(Gbf + r * HH);
  float gv[12];
  float s = 0.f, s2 = 0.f;
#pragma unroll
  for (int m = 0; m < 3; ++m) {
    u16x4 q = gr[lane + 64 * m];
#pragma unroll
    for (int j = 0; j < 4; ++j) {
      float f = bf2f(q[j]);
      gv[m * 4 + j] = f;
      s += f; s2 += f * f;
    }
  }
#pragma unroll
  for (int off = 32; off >= 1; off >>= 1) {
    s  += __shfl_xor(s, off);
    s2 += __shfl_xor(s2, off);
  }
  float mu  = s * (1.f / HH);
  float var = s2 * (1.f / HH) - mu * mu;
  float rs  = rsqrtf(var + 1e-5f);
  const float4* w4 = (const float4*)w;
  const float4* b4 = (const float4*)b;
  const u16x4* br = (const u16x4*)(basebf + r * HH);
  float4* xr = (float4*)(out + r * HH);
#pragma unroll
  for (int m = 0; m < 3; ++m) {
    float4 ww = w4[lane + 64 * m], bb = b4[lane + 64 * m];
    u16x4 bq = br[lane + 64 * m];
    float4 xv;
    xv.x = bf2f(bq[0]) + (gv[m * 4 + 0] - mu) * rs * ww.x + bb.x;
    xv.y = bf2f(bq[1]) + (gv[m * 4 + 1] - mu) * rs * ww.y + bb.y;
    xv.z = bf2f(bq[2]) + (gv[m * 4 + 2] - mu) * rs * ww.z + bb.z;
    xv.w = bf2f(bq[3]) + (gv[m * 4 + 3] - mu) * rs * ww.w + bb.w;
    xr[lane + 64 * m] = xv;
  }
}

// ---------------------------------------------------------------------------
// MFMA Toeplitz conv + D*u + gelu.  One wg per h.  Output bf16 [B,H,L].
// ---------------------------------------------------------------------------
__global__ __launch_bounds__(256) void conv_mfma_kernel(
    const ushort* __restrict__ Ubf, const ushort* __restrict__ rev,
    const float* __restrict__ Dv, ushort* __restrict__ Cbf) {
  __shared__ ushort Ulds[32 * 512];    // 32 KB
  __shared__ ushort Ktab[8 * 1048];    // 16.4 KB
  int tid = threadIdx.x;
  int w = tid >> 6, lane = tid & 63;
  int h = blockIdx.x;

#pragma unroll
  for (int it = 0; it < 8; ++it) {
    int G = it * 256 + tid;
    int b = G >> 6, cg = G & 63;
    gload16(Ubf + (((size_t)b * HH + h) << 9) + ((cg ^ (b & 7)) << 3),
            (char*)Ulds + (size_t)(it * 256 + (tid & 0xFFC0)) * 16);
  }
  const ushort* revh = rev + ((size_t)h << 10);
#pragma unroll
  for (int it = 0; it < 5; ++it) {
    int G = it * 256 + tid;
    if (G < 1048) {
      int r = G / 131, pg = G - r * 131;
      int se = (pg << 3) - 17 - r;
      se = se < 0 ? 0 : (se > 1016 ? 1016 : se);
      gload16(revh + se, (char*)Ktab + (size_t)(it * 256 + (tid & 0xFFC0)) * 16);
    }
  }
  asm volatile("s_waitcnt vmcnt(0)" ::: "memory");
  __syncthreads();

  int cc = lane & 15, g = lane >> 4;
  int wt = w << 7;
  const char* kbase = (const char*)Ktab + (cc & 7) * 2096 - ((cc >> 3) << 4)
                      + (g << 4) + 2 * (528 - wt);
  const char* ubase = (const char*)Ulds;
  int usw = (cc & 7) << 4;

  f32x4 acc[8][2];
#pragma unroll
  for (int m = 0; m < 8; ++m)
#pragma unroll
    for (int n = 0; n < 2; ++n) acc[m][n] = (f32x4){0.f, 0.f, 0.f, 0.f};

  bf16x8 A[8];
#define LDA(slot, m, ks) A[slot] = *(const bf16x8*)(kbase - (m) * 32 + (ks) * 64)
  LDA(0, 0, 0); LDA(1, 1, 0); LDA(2, 2, 0); LDA(3, 3, 0);
  LDA(4, 4, 0); LDA(5, 5, 0); LDA(6, 6, 0); LDA(7, 7, 0);
#pragma unroll
  for (int ks = 0; ks < 16; ++ks) {
    if (ks > 0) {
      LDA((0 - 2 * ks) & 7, 0, ks);
      LDA((1 - 2 * ks) & 7, 1, ks);
    }
    int ub = ((ks << 6) + (g << 4)) ^ usw;
    bf16x8 B0 = *(const bf16x8*)(ubase + cc * 1024 + ub);
    bf16x8 B1 = *(const bf16x8*)(ubase + (16 + cc) * 1024 + ub);
#pragma unroll
    for (int m = 0; m < 8; ++m) {
      acc[m][0] = __builtin_amdgcn_mfma_f32_16x16x32_bf16(
          A[(m - 2 * ks) & 7], B0, acc[m][0], 0, 0, 0);
      acc[m][1] = __builtin_amdgcn_mfma_f32_16x16x32_bf16(
          A[(m - 2 * ks) & 7], B1, acc[m][1], 0, 0, 0);
    }
  }
#undef LDA

  float dh = Dv[h];
  const float c1 = 2.3021181306612f, c3 = 0.1029392186f;
#pragma unroll
  for (int n = 0; n < 2; ++n) {
    int b = (n << 4) + cc;
    const char* up = (const char*)Ulds + b * 1024;
#pragma unroll
    for (int m = 0; m < 8; ++m) {
      int t0 = wt + (m << 4) + (g << 2);
      u16x4 uq = *(const u16x4*)(up + ((t0 << 1) ^ usw));
      u16x4 o;
#pragma unroll
      for (int r = 0; r < 4; ++r) {
        float y = acc[m][n][r] + dh * bf2f(uq[r]);
        float e = __builtin_amdgcn_exp2f(-(c1 * y + c3 * y * y * y));
        float gg = y * __builtin_amdgcn_rcpf(1.f + e);
        o[r] = f2bf(gg);
      }
      *(u16x4*)(Cbf + (((size_t)b * HH + h) << 9) + t0) = o;
    }
  }
}

// ---------------------------------------------------------------------------
// bf16 [B,H,L] -> bf16 [B,L,H]
// ---------------------------------------------------------------------------
__global__ __launch_bounds__(256) void t2bf_bf_kernel(
    const ushort* __restrict__ C, ushort* __restrict__ Y) {
  __shared__ ushort tile[32][34];
  int b = blockIdx.z;
  int h0 = blockIdx.x << 5, l0 = blockIdx.y << 5;
  int tx = threadIdx.x, ty = threadIdx.y;
#pragma unroll
  for (int k = 0; k < 4; ++k)
    tile[ty + 8 * k][tx] = C[(((size_t)b * HH + h0 + ty + 8 * k) << 9) + l0 + tx];
  __syncthreads();
#pragma unroll
  for (int k = 0; k < 4; ++k)
    Y[((size_t)b * LL + l0 + ty + 8 * k) * HH + h0 + tx] = tile[tx][ty + 8 * k];
}

// ---------------------------------------------------------------------------
// bf16 MFMA GEMM: Gbf[b,l,o] = bf16( Ybf[b,l,:]*Wbf[o,:] + bias )
// ---------------------------------------------------------------------------
__global__ __launch_bounds__(256) void gemm_kernel(
    const ushort* __restrict__ Ybf, const ushort* __restrict__ Wbf,
    const float* __restrict__ bias, ushort* __restrict__ Gb) {
  __shared__ ushort As[128 * 64];
  __shared__ ushort Bs[128 * 64];
  int tid = threadIdx.x;
  int wv = tid >> 6, lane = tid & 63;
  int wm = wv >> 1, wn = wv & 1;
  int b  = blockIdx.y >> 2;
  int l0 = (blockIdx.y & 3) << 7;
  int o0 = blockIdx.x << 7;

  int swz8 = (((lane & 7) ^ (lane >> 3)) << 3);
  int rsub = (lane >> 3);
  size_t arow0 = (size_t)(b * LL + l0 + wv * 32 + rsub) * HH;
  size_t brow0 = (size_t)(o0 + wv * 32 + rsub) * HH;
  char* Adst = (char*)As + wv * 4096;
  char* Bdst = (char*)Bs + wv * 4096;

  f32x4 acc[4][4];
#pragma unroll
  for (int i = 0; i < 4; ++i)
#pragma unroll
    for (int j = 0; j < 4; ++j) acc[i][j] = (f32x4){0.f, 0.f, 0.f, 0.f};

  for (int kt = 0; kt < HH / 64; ++kt) {
    int h0 = kt * 64;
#pragma unroll
    for (int i = 0; i < 4; ++i) {
      gload16(Ybf + arow0 + (size_t)i * 8 * HH + h0 + swz8, Adst + i * 1024);
      gload16(Wbf + brow0 + (size_t)i * 8 * HH + h0 + swz8, Bdst + i * 1024);
    }
    __syncthreads();

    bf16x8 af[4][2], bfr[4][2];
#pragma unroll
    for (int mi = 0; mi < 4; ++mi) {
      int m = wm * 64 + mi * 16 + (lane & 15);
#pragma unroll
      for (int kk = 0; kk < 2; ++kk) {
        int off = m * 128 + ((((lane >> 4) << 4) + (kk << 6)) ^ ((lane & 7) << 4));
        af[mi][kk] = *(const bf16x8*)((const char*)As + off);
      }
    }
#pragma unroll
    for (int ni = 0; ni < 4; ++ni) {
      int n = wn * 64 + ni * 16 + (lane & 15);
#pragma unroll
      for (int kk = 0; kk < 2; ++kk) {
        int off = n * 128 + ((((lane >> 4) << 4) + (kk << 6)) ^ ((lane & 7) << 4));
        bfr[ni][kk] = *(const bf16x8*)((const char*)Bs + off);
      }
    }
#pragma unroll
    for (int kk = 0; kk < 2; ++kk)
#pragma unroll
      for (int mi = 0; mi < 4; ++mi)
#pragma unroll
        for (int ni = 0; ni < 4; ++ni)
          acc[mi][ni] = __builtin_amdgcn_mfma_f32_16x16x32_bf16(
              af[mi][kk], bfr[ni][kk], acc[mi][ni], 0, 0, 0);
    __syncthreads();
  }

#pragma unroll
  for (int ni = 0; ni < 4; ++ni) {
    int n_g = o0 + wn * 64 + ni * 16 + (lane & 15);
    float bv = bias[n_g];
#pragma unroll
    for (int mi = 0; mi < 4; ++mi) {
      int m_g = l0 + wm * 64 + mi * 16 + ((lane >> 4) << 2);
      ushort* gp = Gb + ((size_t)b * LL + m_g) * HH + n_g;
#pragma unroll
      for (int j = 0; j < 4; ++j)
        gp[(size_t)j * HH] = f2bf(acc[mi][ni][j] + bv);
    }
  }
}

// ---------------------------------------------------------------------------
extern "C" void kernel_launch(void* const* d_in, const int* in_sizes, int n_in,
                              void* d_out, int out_size, void* d_ws, size_t ws_size,
                              hipStream_t stream) {
  const float* x      = (const float*)d_in[0];
  const int*   mask   = (const int*)d_in[1];
  const float* ln1_w  = (const float*)d_in[2];
  const float* ln1_b  = (const float*)d_in[3];
  const float* log_dt = (const float*)d_in[4];
  const float* A_re   = (const float*)d_in[5];
  const float* A_im   = (const float*)d_in[6];
  const float* C_re   = (const float*)d_in[7];
  const float* C_im   = (const float*)d_in[8];
  const float* Dv     = (const float*)d_in[9];
  const float* Wout   = (const float*)d_in[10];
  const float* bout   = (const float*)d_in[11];
  const float* ln2_w  = (const float*)d_in[12];
  const float* ln2_b  = (const float*)d_in[13];
  float* out = (float*)d_out;

  // ws: rev | Ubf (reused as Ybf) | Cbf | Wbf | Gbf | Obf
  ushort* rev  = (ushort*)d_ws;                               // NL*H*1024
  ushort* Ubf  = rev + (size_t)NLAYERS * HH * 1024;           // B*H*L
  ushort* Cbf  = Ubf + (size_t)BB * HH * LL;                  // B*H*L
  ushort* Wbf  = Cbf + (size_t)BB * HH * LL;                  // NL*H*H
  ushort* Gbf  = Wbf + (size_t)NLAYERS * HH * HH;             // B*L*H
  ushort* Obf  = Gbf + (size_t)BB * LL * HH;                  // B*L*H residual
  ushort* Ybf  = Ubf;   // safe reuse: conv consumed Ubf before t2bf writes it

  compute_k_kernel<<<NLAYERS * HH, 256, 0, stream>>>(
      log_dt, A_re, A_im, C_re, C_im, rev);
  wcast_kernel<<<(NLAYERS * HH * HH) / (256 * 8), 256, 0, stream>>>(Wout, Wbf);

  ln_t_kernel<<<dim3(LL / 32, BB), 256, 0, stream>>>(
      x, ln1_w, ln1_b, mask, Ubf);

  for (int il = 0; il < NLAYERS; ++il) {
    conv_mfma_kernel<<<HH, 256, 0, stream>>>(
        Ubf, rev + (size_t)il * HH * 1024, Dv + il * HH, Cbf);
    t2bf_bf_kernel<<<dim3(HH / 32, LL / 32, BB), dim3(32, 8), 0, stream>>>(Cbf, Ybf);
    gemm_kernel<<<dim3(HH / 128, BB * LL / 128), 256, 0, stream>>>(
        Ybf, Wbf + (size_t)il * HH * HH, bout + il * HH, Gbf);
    if (il == 0) {
      res_lnt_kernel<true><<<dim3(LL / 32, BB), 256, 0, stream>>>(
          Gbf, ln2_w, ln2_b, x, Obf, mask, ln1_w + HH, ln1_b + HH, Ubf);
    } else if (il < NLAYERS - 1) {
      res_lnt_kernel<false><<<dim3(LL / 32, BB), 256, 0, stream>>>(
          Gbf, ln2_w + il * HH, ln2_b + il * HH, Obf, Obf, mask,
          ln1_w + (il + 1) * HH, ln1_b + (il + 1) * HH, Ubf);
    } else {
      ln_res_kernel<<<BB * LL / 4, 256, 0, stream>>>(
          Gbf, ln2_w + il * HH, ln2_b + il * HH, Obf, out);
    }
  }
}

// Round 8
// 495.301 us; speedup vs baseline: 1.1313x; 1.1313x over previous
//
#include <hip/hip_runtime.h>
#include <math.h>

#define BB 32
#define LL 512
#define HH 768
#define NN 64
#define NLAYERS 4

typedef unsigned short ushort;
typedef __attribute__((ext_vector_type(8))) short bf16x8;
typedef __attribute__((ext_vector_type(4))) float f32x4;
typedef __attribute__((ext_vector_type(4))) ushort u16x4;

static __device__ __forceinline__ ushort f2bf(float f) {
  union { float f; unsigned u; } v; v.f = f;
  unsigned r = (v.u + 0x7FFF + ((v.u >> 16) & 1)) >> 16;   // RNE
  return (ushort)r;
}
static __device__ __forceinline__ float bf2f(ushort u) {
  union { unsigned u; float f; } v; v.u = ((unsigned)u) << 16; return v.f;
}
static __device__ __forceinline__ void gload16(const void* g, void* l) {
  __builtin_amdgcn_global_load_lds(
      (const __attribute__((address_space(1))) unsigned int*)g,
      (__attribute__((address_space(3))) unsigned int*)l, 16, 0, 0);
}
static __device__ __forceinline__ float hw_sin(float f) {
  float r; asm("v_sin_f32 %0, %1" : "=v"(r) : "v"(f)); return r;
}
static __device__ __forceinline__ float hw_cos(float f) {
  float r; asm("v_cos_f32 %0, %1" : "=v"(r) : "v"(f)); return r;
}

// ---------------------------------------------------------------------------
// compute_k v4 (unchanged from round 7): one wg per (il,h).
// rev[i] = bf16(Kb[1023-i]); Kb[512+d]=K0[d], Kb[511-m]=K1[m].
// ---------------------------------------------------------------------------
__global__ __launch_bounds__(256) void compute_k_kernel(
    const float* __restrict__ log_dt, const float* __restrict__ A_re,
    const float* __restrict__ A_im, const float* __restrict__ C_re,
    const float* __restrict__ C_im, ushort* __restrict__ rev) {
  __shared__ float vr_[64 * 64];
  __shared__ float vi_[64 * 64];
  __shared__ float ctab[64][8];
  __shared__ float red[3][64][17];
  int tid = threadIdx.x;
  int wid = tid >> 6, lane = tid & 63;
  int blk = blockIdx.x;             // il*HH + h
  int il = blk / HH, h = blk - il * HH;
  {
    int n = lane;
    float dt = expf(log_dt[blk]);
    float a_re = -expf(A_re[(size_t)blk * NN + n]);
    float a_im = A_im[(size_t)blk * NN + n];
    float er = dt * a_re, ei = dt * a_im;
    float ea = __builtin_amdgcn_exp2f(er * 1.4426950408889634f);
    float fr = ei * 0.15915494309189535f;    // revolutions
    fr = fr - floorf(fr);
    float sv = hw_sin(fr), cv = hw_cos(fr);
    float qr = ea * cv, qi = ea * sv;
    if (wid == 0) {
      float e1r = qr - 1.f, e1i = qi;
      float den = a_re * a_re + a_im * a_im;
      float wr = (e1r * a_re + e1i * a_im) / den;
      float wi = (e1i * a_re - e1r * a_im) / den;
      size_t c0 = ((size_t)(il * 2 + 0) * HH + h) * NN + n;
      size_t c1 = ((size_t)(il * 2 + 1) * HH + h) * NN + n;
      float c0r = C_re[c0], c0i = C_im[c0];
      float c1r = C_re[c1], c1i = C_im[c1];
      ctab[n][0] = qr; ctab[n][1] = qi;
      ctab[n][2] = 2.f * (c0r * wr - c0i * wi);
      ctab[n][3] = 2.f * (c0r * wi + c0i * wr);
      ctab[n][4] = 2.f * (c1r * wr - c1i * wi);
      ctab[n][5] = 2.f * (c1r * wi + c1i * wr);
    }
    float pr = qr, pi = qi;
    float q8r = 0.f, q8i = 0.f, q128r = 0.f, q128i = 0.f, q256r = 0.f, q256i = 0.f;
#pragma unroll
    for (int j = 0; j < 8; ++j) {
      float nr = pr * pr - pi * pi, ni = 2.f * pr * pi;
      pr = nr; pi = ni;
      if (j == 2) { q8r = pr; q8i = pi; }
      if (j == 6) { q128r = pr; q128i = pi; }
      if (j == 7) { q256r = pr; q256i = pi; }
    }
    float sr, si;
    if (wid == 0)      { sr = 1.f;   si = 0.f; }
    else if (wid == 1) { sr = q128r; si = q128i; }
    else if (wid == 2) { sr = q256r; si = q256i; }
    else { sr = q128r * q256r - q128i * q256i; si = q128r * q256i + q128i * q256r; }
#pragma unroll
    for (int j = 0; j < 16; ++j) {
      int t = wid * 16 + j;
      vr_[t * 64 + (n ^ t)] = sr;
      vi_[t * 64 + (n ^ t)] = si;
      float nr = sr * q8r - si * q8i, ni = sr * q8i + si * q8r;
      sr = nr; si = ni;
    }
  }
  __syncthreads();
  float k0[8], k1[8];
#pragma unroll
  for (int s = 0; s < 8; ++s) { k0[s] = 0.f; k1[s] = 0.f; }
  int t = lane;
  for (int nn = 0; nn < 16; ++nn) {
    int n = wid * 16 + nn;
    float4 cA = *(const float4*)&ctab[n][0];
    float c1wr = ctab[n][4], c1wi = ctab[n][5];
    float vr = vr_[t * 64 + (n ^ t)];
    float vi = vi_[t * 64 + (n ^ t)];
#pragma unroll
    for (int s = 0; s < 8; ++s) {
      k0[s] = fmaf(cA.z, vr, fmaf(-cA.w, vi, k0[s]));
      k1[s] = fmaf(c1wr, vr, fmaf(-c1wi, vi, k1[s]));
      float nr = vr * cA.x - vi * cA.y, ni = vr * cA.y + vi * cA.x;
      vr = nr; vi = ni;
    }
  }
  if (wid > 0) {
#pragma unroll
    for (int s = 0; s < 8; ++s) {
      red[wid - 1][lane][s] = k0[s];
      red[wid - 1][lane][8 + s] = k1[s];
    }
  }
  __syncthreads();
  if (wid == 0) {
#pragma unroll
    for (int w = 0; w < 3; ++w)
#pragma unroll
      for (int s = 0; s < 8; ++s) {
        k0[s] += red[w][lane][s];
        k1[s] += red[w][lane][8 + s];
      }
    ushort* row = rev + ((size_t)blk << 10);
    bf16x8 o0, o1;
#pragma unroll
    for (int i = 0; i < 8; ++i) {
      o0[i] = (short)f2bf(k0[7 - i]);
      o1[i] = (short)f2bf(k1[i]);
    }
    *(bf16x8*)(row + 504 - 8 * t) = o0;
    *(bf16x8*)(row + 512 + 8 * t) = o1;
  }
}

// ---------------------------------------------------------------------------
// Wout fp32 -> bf16 (once)
// ---------------------------------------------------------------------------
__global__ __launch_bounds__(256) void wcast_kernel(
    const float* __restrict__ W, ushort* __restrict__ Wbf) {
  size_t i = ((size_t)blockIdx.x * 256 + threadIdx.x) * 8;
  float4 a = *(const float4*)&W[i];
  float4 c = *(const float4*)&W[i + 4];
  ushort o[8] = {f2bf(a.x), f2bf(a.y), f2bf(a.z), f2bf(a.w),
                 f2bf(c.x), f2bf(c.y), f2bf(c.z), f2bf(c.w)};
  *(bf16x8*)&Wbf[i] = *(bf16x8*)o;
}

// ---------------------------------------------------------------------------
// Fused LN1 * mask + transpose + bf16: X f32 [B,L,H] -> U bf16 [B,H,L]
// (layer 0 only)
// ---------------------------------------------------------------------------
__global__ __launch_bounds__(256) void ln_t_kernel(
    const float* __restrict__ X, const float* __restrict__ w,
    const float* __restrict__ b, const int* __restrict__ mask,
    ushort* __restrict__ U) {
  __shared__ ushort tile[32][772];
  int bb = blockIdx.y;
  int l0 = blockIdx.x << 5;
  int wv = threadIdx.x >> 6, lane = threadIdx.x & 63;
  const float4* w4 = (const float4*)w;
  const float4* b4 = (const float4*)b;
  float4 WW[3], BV[3];
#pragma unroll
  for (int m = 0; m < 3; ++m) { WW[m] = w4[lane + 64 * m]; BV[m] = b4[lane + 64 * m]; }
#pragma unroll
  for (int i = 0; i < 8; ++i) {
    int r = (wv << 3) + i;
    size_t rowi = (size_t)bb * LL + l0 + r;
    const float4* xr = (const float4*)(X + rowi * HH);
    float4 v[3];
    float s = 0.f, s2 = 0.f;
#pragma unroll
    for (int m = 0; m < 3; ++m) {
      v[m] = xr[lane + 64 * m];
      s  += v[m].x + v[m].y + v[m].z + v[m].w;
      s2 += v[m].x * v[m].x + v[m].y * v[m].y + v[m].z * v[m].z + v[m].w * v[m].w;
    }
#pragma unroll
    for (int off = 32; off >= 1; off >>= 1) {
      s  += __shfl_xor(s, off);
      s2 += __shfl_xor(s2, off);
    }
    float mu  = s * (1.f / HH);
    float var = s2 * (1.f / HH) - mu * mu;
    float rs  = rsqrtf(var + 1e-5f);
    float mf  = (float)mask[rowi];
#pragma unroll
    for (int m = 0; m < 3; ++m) {
      u16x4 o;
      o.x = f2bf(((v[m].x - mu) * rs * WW[m].x + BV[m].x) * mf);
      o.y = f2bf(((v[m].y - mu) * rs * WW[m].y + BV[m].y) * mf);
      o.z = f2bf(((v[m].z - mu) * rs * WW[m].z + BV[m].z) * mf);
      o.w = f2bf(((v[m].w - mu) * rs * WW[m].w + BV[m].w) * mf);
      *(u16x4*)&tile[r][(lane + 64 * m) << 2] = o;
    }
  }
  __syncthreads();
#pragma unroll
  for (int it = 0; it < 3; ++it) {
    int h = it * 256 + threadIdx.x;
    ushort* dst = U + (((size_t)bb * HH + h) << 9) + l0;
#pragma unroll
    for (int c = 0; c < 4; ++c) {
      bf16x8 o;
#pragma unroll
      for (int j = 0; j < 8; ++j) o[j] = (short)tile[c * 8 + j][h];
      *(bf16x8*)(dst + (c << 3)) = o;
    }
  }
}

// ---------------------------------------------------------------------------
// Boundary fuse: out_bf = base + LN2(Gbf);  U = transpose(bf16(LN1(out)*mask))
// All register math via explicit components (NO address-of on register
// vectors -- round-7's cast pattern forced W2/B2 to scratch, 60us/dispatch).
// ---------------------------------------------------------------------------
template <bool BASE_F32>
__global__ __launch_bounds__(256) void res_lnt_kernel(
    const ushort* __restrict__ Gbf, const float* __restrict__ w2,
    const float* __restrict__ b2, const void* __restrict__ base_,
    ushort* __restrict__ outbf, const int* __restrict__ mask,
    const float* __restrict__ w1, const float* __restrict__ b1,
    ushort* __restrict__ U) {
  __shared__ ushort tile[32][772];
  int bb = blockIdx.y;
  int l0 = blockIdx.x << 5;
  int wv = threadIdx.x >> 6, lane = threadIdx.x & 63;
  const float4* w14 = (const float4*)w1;
  const float4* b14 = (const float4*)b1;
  const float4* w24 = (const float4*)w2;
  const float4* b24 = (const float4*)b2;
  float4 W1[3], B1[3], W2[3], B2[3];
#pragma unroll
  for (int m = 0; m < 3; ++m) {
    W1[m] = w14[lane + 64 * m]; B1[m] = b14[lane + 64 * m];
    W2[m] = w24[lane + 64 * m]; B2[m] = b24[lane + 64 * m];
  }
#pragma unroll
  for (int i = 0; i < 8; ++i) {
    int r = (wv << 3) + i;
    size_t rowi = (size_t)bb * LL + l0 + r;
    // LN2 stats over G row
    const u16x4* gr = (const u16x4*)(Gbf + rowi * HH);
    float4 gvv[3];
    float s = 0.f, s2 = 0.f;
#pragma unroll
    for (int m = 0; m < 3; ++m) {
      u16x4 q = gr[lane + 64 * m];
      float4 g;
      g.x = bf2f(q[0]); g.y = bf2f(q[1]); g.z = bf2f(q[2]); g.w = bf2f(q[3]);
      gvv[m] = g;
      s  += g.x + g.y + g.z + g.w;
      s2 += g.x * g.x + g.y * g.y + g.z * g.z + g.w * g.w;
    }
#pragma unroll
    for (int off = 32; off >= 1; off >>= 1) {
      s  += __shfl_xor(s, off);
      s2 += __shfl_xor(s2, off);
    }
    float mu2  = s * (1.f / HH);
    float var2 = s2 * (1.f / HH) - mu2 * mu2;
    float rs2  = rsqrtf(var2 + 1e-5f);
    // out = base + LN2(G); accumulate LN1 stats
    float4 ovv[3];
    float t1 = 0.f, t2 = 0.f;
#pragma unroll
    for (int m = 0; m < 3; ++m) {
      float4 bv;
      if (BASE_F32) {
        bv = ((const float4*)((const float*)base_ + rowi * HH))[lane + 64 * m];
      } else {
        u16x4 bq = ((const u16x4*)((const ushort*)base_ + rowi * HH))[lane + 64 * m];
        bv.x = bf2f(bq[0]); bv.y = bf2f(bq[1]); bv.z = bf2f(bq[2]); bv.w = bf2f(bq[3]);
      }
      float4 o;
      o.x = bv.x + (gvv[m].x - mu2) * rs2 * W2[m].x + B2[m].x;
      o.y = bv.y + (gvv[m].y - mu2) * rs2 * W2[m].y + B2[m].y;
      o.z = bv.z + (gvv[m].z - mu2) * rs2 * W2[m].z + B2[m].z;
      o.w = bv.w + (gvv[m].w - mu2) * rs2 * W2[m].w + B2[m].w;
      ovv[m] = o;
      t1 += o.x + o.y + o.z + o.w;
      t2 += o.x * o.x + o.y * o.y + o.z * o.z + o.w * o.w;
      u16x4 ob;
      ob[0] = f2bf(o.x); ob[1] = f2bf(o.y); ob[2] = f2bf(o.z); ob[3] = f2bf(o.w);
      ((u16x4*)(outbf + rowi * HH))[lane + 64 * m] = ob;
    }
#pragma unroll
    for (int off = 32; off >= 1; off >>= 1) {
      t1 += __shfl_xor(t1, off);
      t2 += __shfl_xor(t2, off);
    }
    float mu1  = t1 * (1.f / HH);
    float var1 = t2 * (1.f / HH) - mu1 * mu1;
    float rs1  = rsqrtf(var1 + 1e-5f);
    float mf   = (float)mask[rowi];
#pragma unroll
    for (int m = 0; m < 3; ++m) {
      u16x4 o;
      o[0] = f2bf(((ovv[m].x - mu1) * rs1 * W1[m].x + B1[m].x) * mf);
      o[1] = f2bf(((ovv[m].y - mu1) * rs1 * W1[m].y + B1[m].y) * mf);
      o[2] = f2bf(((ovv[m].z - mu1) * rs1 * W1[m].z + B1[m].z) * mf);
      o[3] = f2bf(((ovv[m].w - mu1) * rs1 * W1[m].w + B1[m].w) * mf);
      *(u16x4*)&tile[r][(lane + 64 * m) << 2] = o;
    }
  }
  __syncthreads();
#pragma unroll
  for (int it = 0; it < 3; ++it) {
    int h = it * 256 + threadIdx.x;
    ushort* dst = U + (((size_t)bb * HH + h) << 9) + l0;
#pragma unroll
    for (int c = 0; c < 4; ++c) {
      bf16x8 o;
#pragma unroll
      for (int j = 0; j < 8; ++j) o[j] = (short)tile[c * 8 + j][h];
      *(bf16x8*)(dst + (c << 3)) = o;
    }
  }
}

// ---------------------------------------------------------------------------
// Final: out_f32 = base_bf + LN2(Gbf)
// ---------------------------------------------------------------------------
__global__ __launch_bounds__(256) void ln_res_kernel(
    const ushort* __restrict__ Gbf, const float* __restrict__ w,
    const float* __restrict__ b, const ushort* __restrict__ basebf,
    float* __restrict__ out) {
  int wv = threadIdx.x >> 6, lane = threadIdx.x & 63;
  size_t r = (size_t)blockIdx.x * 4 + wv;
  const u16x4* gr = (const u16x4*)(Gbf + r * HH);
  float4 gvv[3];
  float s = 0.f, s2 = 0.f;
#pragma unroll
  for (int m = 0; m < 3; ++m) {
    u16x4 q = gr[lane + 64 * m];
    float4 g;
    g.x = bf2f(q[0]); g.y = bf2f(q[1]); g.z = bf2f(q[2]); g.w = bf2f(q[3]);
    gvv[m] = g;
    s  += g.x + g.y + g.z + g.w;
    s2 += g.x * g.x + g.y * g.y + g.z * g.z + g.w * g.w;
  }
#pragma unroll
  for (int off = 32; off >= 1; off >>= 1) {
    s  += __shfl_xor(s, off);
    s2 += __shfl_xor(s2, off);
  }
  float mu  = s * (1.f / HH);
  float var = s2 * (1.f / HH) - mu * mu;
  float rs  = rsqrtf(var + 1e-5f);
  const float4* w4 = (const float4*)w;
  const float4* b4 = (const float4*)b;
  const u16x4* br = (const u16x4*)(basebf + r * HH);
  float4* xr = (float4*)(out + r * HH);
#pragma unroll
  for (int m = 0; m < 3; ++m) {
    float4 ww = w4[lane + 64 * m], bb = b4[lane + 64 * m];
    u16x4 bq = br[lane + 64 * m];
    float4 xv;
    xv.x = bf2f(bq[0]) + (gvv[m].x - mu) * rs * ww.x + bb.x;
    xv.y = bf2f(bq[1]) + (gvv[m].y - mu) * rs * ww.y + bb.y;
    xv.z = bf2f(bq[2]) + (gvv[m].z - mu) * rs * ww.z + bb.z;
    xv.w = bf2f(bq[3]) + (gvv[m].w - mu) * rs * ww.w + bb.w;
    xr[lane + 64 * m] = xv;
  }
}

// ---------------------------------------------------------------------------
// MFMA Toeplitz conv + D*u + gelu.  One wg per h.  Output bf16 [B,H,L].
// ---------------------------------------------------------------------------
__global__ __launch_bounds__(256) void conv_mfma_kernel(
    const ushort* __restrict__ Ubf, const ushort* __restrict__ rev,
    const float* __restrict__ Dv, ushort* __restrict__ Cbf) {
  __shared__ ushort Ulds[32 * 512];    // 32 KB
  __shared__ ushort Ktab[8 * 1048];    // 16.4 KB
  int tid = threadIdx.x;
  int w = tid >> 6, lane = tid & 63;
  int h = blockIdx.x;

#pragma unroll
  for (int it = 0; it < 8; ++it) {
    int G = it * 256 + tid;
    int b = G >> 6, cg = G & 63;
    gload16(Ubf + (((size_t)b * HH + h) << 9) + ((cg ^ (b & 7)) << 3),
            (char*)Ulds + (size_t)(it * 256 + (tid & 0xFFC0)) * 16);
  }
  const ushort* revh = rev + ((size_t)h << 10);
#pragma unroll
  for (int it = 0; it < 5; ++it) {
    int G = it * 256 + tid;
    if (G < 1048) {
      int r = G / 131, pg = G - r * 131;
      int se = (pg << 3) - 17 - r;
      se = se < 0 ? 0 : (se > 1016 ? 1016 : se);
      gload16(revh + se, (char*)Ktab + (size_t)(it * 256 + (tid & 0xFFC0)) * 16);
    }
  }
  asm volatile("s_waitcnt vmcnt(0)" ::: "memory");
  __syncthreads();

  int cc = lane & 15, g = lane >> 4;
  int wt = w << 7;
  const char* kbase = (const char*)Ktab + (cc & 7) * 2096 - ((cc >> 3) << 4)
                      + (g << 4) + 2 * (528 - wt);
  const char* ubase = (const char*)Ulds;
  int usw = (cc & 7) << 4;

  f32x4 acc[8][2];
#pragma unroll
  for (int m = 0; m < 8; ++m)
#pragma unroll
    for (int n = 0; n < 2; ++n) acc[m][n] = (f32x4){0.f, 0.f, 0.f, 0.f};

  bf16x8 A[8];
#define LDA(slot, m, ks) A[slot] = *(const bf16x8*)(kbase - (m) * 32 + (ks) * 64)
  LDA(0, 0, 0); LDA(1, 1, 0); LDA(2, 2, 0); LDA(3, 3, 0);
  LDA(4, 4, 0); LDA(5, 5, 0); LDA(6, 6, 0); LDA(7, 7, 0);
#pragma unroll
  for (int ks = 0; ks < 16; ++ks) {
    if (ks > 0) {
      LDA((0 - 2 * ks) & 7, 0, ks);
      LDA((1 - 2 * ks) & 7, 1, ks);
    }
    int ub = ((ks << 6) + (g << 4)) ^ usw;
    bf16x8 B0 = *(const bf16x8*)(ubase + cc * 1024 + ub);
    bf16x8 B1 = *(const bf16x8*)(ubase + (16 + cc) * 1024 + ub);
#pragma unroll
    for (int m = 0; m < 8; ++m) {
      acc[m][0] = __builtin_amdgcn_mfma_f32_16x16x32_bf16(
          A[(m - 2 * ks) & 7], B0, acc[m][0], 0, 0, 0);
      acc[m][1] = __builtin_amdgcn_mfma_f32_16x16x32_bf16(
          A[(m - 2 * ks) & 7], B1, acc[m][1], 0, 0, 0);
    }
  }
#undef LDA

  float dh = Dv[h];
  const float c1 = 2.3021181306612f, c3 = 0.1029392186f;
#pragma unroll
  for (int n = 0; n < 2; ++n) {
    int b = (n << 4) + cc;
    const char* up = (const char*)Ulds + b * 1024;
#pragma unroll
    for (int m = 0; m < 8; ++m) {
      int t0 = wt + (m << 4) + (g << 2);
      u16x4 uq = *(const u16x4*)(up + ((t0 << 1) ^ usw));
      u16x4 o;
#pragma unroll
      for (int r = 0; r < 4; ++r) {
        float y = acc[m][n][r] + dh * bf2f(uq[r]);
        float e = __builtin_amdgcn_exp2f(-(c1 * y + c3 * y * y * y));
        float gg = y * __builtin_amdgcn_rcpf(1.f + e);
        o[r] = f2bf(gg);
      }
      *(u16x4*)(Cbf + (((size_t)b * HH + h) << 9) + t0) = o;
    }
  }
}

// ---------------------------------------------------------------------------
// bf16 [B,H,L] -> bf16 [B,L,H]
// ---------------------------------------------------------------------------
__global__ __launch_bounds__(256) void t2bf_bf_kernel(
    const ushort* __restrict__ C, ushort* __restrict__ Y) {
  __shared__ ushort tile[32][34];
  int b = blockIdx.z;
  int h0 = blockIdx.x << 5, l0 = blockIdx.y << 5;
  int tx = threadIdx.x, ty = threadIdx.y;
#pragma unroll
  for (int k = 0; k < 4; ++k)
    tile[ty + 8 * k][tx] = C[(((size_t)b * HH + h0 + ty + 8 * k) << 9) + l0 + tx];
  __syncthreads();
#pragma unroll
  for (int k = 0; k < 4; ++k)
    Y[((size_t)b * LL + l0 + ty + 8 * k) * HH + h0 + tx] = tile[tx][ty + 8 * k];
}

// ---------------------------------------------------------------------------
// bf16 MFMA GEMM: Gbf[b,l,o] = bf16( Ybf[b,l,:]*Wbf[o,:] + bias )
// ---------------------------------------------------------------------------
__global__ __launch_bounds__(256) void gemm_kernel(
    const ushort* __restrict__ Ybf, const ushort* __restrict__ Wbf,
    const float* __restrict__ bias, ushort* __restrict__ Gb) {
  __shared__ ushort As[128 * 64];
  __shared__ ushort Bs[128 * 64];
  int tid = threadIdx.x;
  int wv = tid >> 6, lane = tid & 63;
  int wm = wv >> 1, wn = wv & 1;
  int b  = blockIdx.y >> 2;
  int l0 = (blockIdx.y & 3) << 7;
  int o0 = blockIdx.x << 7;

  int swz8 = (((lane & 7) ^ (lane >> 3)) << 3);
  int rsub = (lane >> 3);
  size_t arow0 = (size_t)(b * LL + l0 + wv * 32 + rsub) * HH;
  size_t brow0 = (size_t)(o0 + wv * 32 + rsub) * HH;
  char* Adst = (char*)As + wv * 4096;
  char* Bdst = (char*)Bs + wv * 4096;

  f32x4 acc[4][4];
#pragma unroll
  for (int i = 0; i < 4; ++i)
#pragma unroll
    for (int j = 0; j < 4; ++j) acc[i][j] = (f32x4){0.f, 0.f, 0.f, 0.f};

  for (int kt = 0; kt < HH / 64; ++kt) {
    int h0 = kt * 64;
#pragma unroll
    for (int i = 0; i < 4; ++i) {
      gload16(Ybf + arow0 + (size_t)i * 8 * HH + h0 + swz8, Adst + i * 1024);
      gload16(Wbf + brow0 + (size_t)i * 8 * HH + h0 + swz8, Bdst + i * 1024);
    }
    __syncthreads();

    bf16x8 af[4][2], bfr[4][2];
#pragma unroll
    for (int mi = 0; mi < 4; ++mi) {
      int m = wm * 64 + mi * 16 + (lane & 15);
#pragma unroll
      for (int kk = 0; kk < 2; ++kk) {
        int off = m * 128 + ((((lane >> 4) << 4) + (kk << 6)) ^ ((lane & 7) << 4));
        af[mi][kk] = *(const bf16x8*)((const char*)As + off);
      }
    }
#pragma unroll
    for (int ni = 0; ni < 4; ++ni) {
      int n = wn * 64 + ni * 16 + (lane & 15);
#pragma unroll
      for (int kk = 0; kk < 2; ++kk) {
        int off = n * 128 + ((((lane >> 4) << 4) + (kk << 6)) ^ ((lane & 7) << 4));
        bfr[ni][kk] = *(const bf16x8*)((const char*)Bs + off);
      }
    }
#pragma unroll
    for (int kk = 0; kk < 2; ++kk)
#pragma unroll
      for (int mi = 0; mi < 4; ++mi)
#pragma unroll
        for (int ni = 0; ni < 4; ++ni)
          acc[mi][ni] = __builtin_amdgcn_mfma_f32_16x16x32_bf16(
              af[mi][kk], bfr[ni][kk], acc[mi][ni], 0, 0, 0);
    __syncthreads();
  }

#pragma unroll
  for (int ni = 0; ni < 4; ++ni) {
    int n_g = o0 + wn * 64 + ni * 16 + (lane & 15);
    float bv = bias[n_g];
#pragma unroll
    for (int mi = 0; mi < 4; ++mi) {
      int m_g = l0 + wm * 64 + mi * 16 + ((lane >> 4) << 2);
      ushort* gp = Gb + ((size_t)b * LL + m_g) * HH + n_g;
#pragma unroll
      for (int j = 0; j < 4; ++j)
        gp[(size_t)j * HH] = f2bf(acc[mi][ni][j] + bv);
    }
  }
}

// ---------------------------------------------------------------------------
extern "C" void kernel_launch(void* const* d_in, const int* in_sizes, int n_in,
                              void* d_out, int out_size, void* d_ws, size_t ws_size,
                              hipStream_t stream) {
  const float* x      = (const float*)d_in[0];
  const int*   mask   = (const int*)d_in[1];
  const float* ln1_w  = (const float*)d_in[2];
  const float* ln1_b  = (const float*)d_in[3];
  const float* log_dt = (const float*)d_in[4];
  const float* A_re   = (const float*)d_in[5];
  const float* A_im   = (const float*)d_in[6];
  const float* C_re   = (const float*)d_in[7];
  const float* C_im   = (const float*)d_in[8];
  const float* Dv     = (const float*)d_in[9];
  const float* Wout   = (const float*)d_in[10];
  const float* bout   = (const float*)d_in[11];
  const float* ln2_w  = (const float*)d_in[12];
  const float* ln2_b  = (const float*)d_in[13];
  float* out = (float*)d_out;

  // ws: rev | Ubf (reused as Ybf) | Cbf | Wbf | Gbf | Obf
  ushort* rev  = (ushort*)d_ws;                               // NL*H*1024
  ushort* Ubf  = rev + (size_t)NLAYERS * HH * 1024;           // B*H*L
  ushort* Cbf  = Ubf + (size_t)BB * HH * LL;                  // B*H*L
  ushort* Wbf  = Cbf + (size_t)BB * HH * LL;                  // NL*H*H
  ushort* Gbf  = Wbf + (size_t)NLAYERS * HH * HH;             // B*L*H
  ushort* Obf  = Gbf + (size_t)BB * LL * HH;                  // B*L*H residual
  ushort* Ybf  = Ubf;   // safe reuse: conv consumed Ubf before t2bf writes it

  compute_k_kernel<<<NLAYERS * HH, 256, 0, stream>>>(
      log_dt, A_re, A_im, C_re, C_im, rev);
  wcast_kernel<<<(NLAYERS * HH * HH) / (256 * 8), 256, 0, stream>>>(Wout, Wbf);

  ln_t_kernel<<<dim3(LL / 32, BB), 256, 0, stream>>>(
      x, ln1_w, ln1_b, mask, Ubf);

  for (int il = 0; il < NLAYERS; ++il) {
    conv_mfma_kernel<<<HH, 256, 0, stream>>>(
        Ubf, rev + (size_t)il * HH * 1024, Dv + il * HH, Cbf);
    t2bf_bf_kernel<<<dim3(HH / 32, LL / 32, BB), dim3(32, 8), 0, stream>>>(Cbf, Ybf);
    gemm_kernel<<<dim3(HH / 128, BB * LL / 128), 256, 0, stream>>>(
        Ybf, Wbf + (size_t)il * HH * HH, bout + il * HH, Gbf);
    if (il == 0) {
      res_lnt_kernel<true><<<dim3(LL / 32, BB), 256, 0, stream>>>(
          Gbf, ln2_w, ln2_b, x, Obf, mask, ln1_w + HH, ln1_b + HH, Ubf);
    } else if (il < NLAYERS - 1) {
      res_lnt_kernel<false><<<dim3(LL / 32, BB), 256, 0, stream>>>(
          Gbf, ln2_w + il * HH, ln2_b + il * HH, Obf, Obf, mask,
          ln1_w + (il + 1) * HH, ln1_b + (il + 1) * HH, Ubf);
    } else {
      ln_res_kernel<<<BB * LL / 4, 256, 0, stream>>>(
          Gbf, ln2_w + il * HH, ln2_b + il * HH, Obf, out);
    }
  }
}